// Round 7
// baseline (65.894 us; speedup 1.0000x reference)
//
#include <hip/hip_runtime.h>

typedef unsigned short u16;
typedef __attribute__((ext_vector_type(8))) short bf16x8;
typedef __attribute__((ext_vector_type(4))) float f32x4;

__device__ __forceinline__ u16 f2bf(float f) {
    unsigned u = __float_as_uint(f);
    unsigned r = (u + 0x7fffu + ((u >> 16) & 1u)) >> 16;
    return (u16)r;
}
__device__ __forceinline__ float bf2f(u16 h) {
    union { unsigned u; float f; } x; x.u = ((unsigned)h) << 16; return x.f;
}

#define NB 8
#define NC 256
#define NK 9
#define NH 64
#define NW 64
#define NP 4096
#define BAND 320            // 5 rows x 64 px band; |dy|>2 ~ P=4e-10 -> exact escape path
#define SB_STRIDE 328       // u16 stride for in-place bf16 B tile (656B rows)
#define KS_STRIDE 264       // u16 stride for key tile rows (528B)

// ======== pass 1 (fused): blocks [0,512) = kf_gemm, [512,768) = head_meta ========
// XCD affinity: batch b == blockIdx.x & 7 for BOTH halves; sample_pass uses the
// same mapping, so kf16[b] / wgt[b] / offs[b] stay in one XCD's L2.
__global__ __launch_bounds__(256) void prep(const float* __restrict__ key,
                                            const float* __restrict__ query,
                                            const float* __restrict__ gumbel,
                                            const float* __restrict__ w_refer,
                                            const float* __restrict__ b_refer,
                                            const float* __restrict__ w_attn, const float* __restrict__ b_attn,
                                            const float* __restrict__ w_mask, const float* __restrict__ b_mask,
                                            const float* __restrict__ w_off,  const float* __restrict__ b_off,
                                            const int* __restrict__ temp_p,
                                            u16* __restrict__ kf16,
                                            float4* __restrict__ wgt, uint2* __restrict__ offs)
{
    __shared__ __align__(16) char smem[46336];   // max(kf 33792, head 25344+20992)
    const int t = threadIdx.x;
    const int lane = t & 63, wid = t >> 6;
    const int fr = lane & 15, kq = (lane >> 4) << 3;

    if (blockIdx.x < 512) {
        // ---------------- kf16[b][c][px] = bf16(w_refer @ key + b_refer) ----------------
        u16* K_s = (u16*)smem;                 // [px][k] bf16
        const int bid = blockIdx.x;
        const int b   = bid & 7;               // XCD = batch
        const int p0  = (bid >> 3) << 6;
        const int co0w = wid << 6;

        // stage key tile 64px x 256k -> LDS bf16 transposed [px][k]
        #pragma unroll
        for (int rep = 0; rep < 16; ++rep) {
            int k = (rep << 4) + (t >> 4), px4 = (t & 15) << 2;
            float4 v = *(const float4*)&key[((size_t)b * NC + k) * NP + p0 + px4];
            K_s[(px4 + 0) * KS_STRIDE + k] = f2bf(v.x);
            K_s[(px4 + 1) * KS_STRIDE + k] = f2bf(v.y);
            K_s[(px4 + 2) * KS_STRIDE + k] = f2bf(v.z);
            K_s[(px4 + 3) * KS_STRIDE + k] = f2bf(v.w);
        }
        __syncthreads();

        f32x4 acc[4][4];
        #pragma unroll
        for (int i = 0; i < 4; ++i)
            #pragma unroll
            for (int j = 0; j < 4; ++j) acc[i][j] = (f32x4){0.f, 0.f, 0.f, 0.f};

        for (int ks = 0; ks < 8; ++ks) {
            const int k0 = (ks << 5) + kq;
            bf16x8 af[4], bfv[4];
            #pragma unroll
            for (int mi = 0; mi < 4; ++mi) {
                const float* src = &w_refer[(size_t)(co0w + (mi << 4) + fr) * NC + k0];
                float4 v0 = *(const float4*)src;
                float4 v1 = *(const float4*)(src + 4);
                bf16x8 a;
                a[0] = (short)f2bf(v0.x); a[1] = (short)f2bf(v0.y);
                a[2] = (short)f2bf(v0.z); a[3] = (short)f2bf(v0.w);
                a[4] = (short)f2bf(v1.x); a[5] = (short)f2bf(v1.y);
                a[6] = (short)f2bf(v1.z); a[7] = (short)f2bf(v1.w);
                af[mi] = a;
            }
            #pragma unroll
            for (int ni = 0; ni < 4; ++ni)
                bfv[ni] = *(const bf16x8*)&K_s[((ni << 4) + fr) * KS_STRIDE + k0];
            #pragma unroll
            for (int mi = 0; mi < 4; ++mi)
                #pragma unroll
                for (int ni = 0; ni < 4; ++ni)
                    acc[mi][ni] = __builtin_amdgcn_mfma_f32_16x16x32_bf16(af[mi], bfv[ni], acc[mi][ni], 0, 0, 0);
        }
        const int col = lane & 15, rbase = (lane >> 4) << 2;
        #pragma unroll
        for (int mi = 0; mi < 4; ++mi) {
            #pragma unroll
            for (int rr = 0; rr < 4; ++rr) {
                int co = co0w + (mi << 4) + rbase + rr;
                float bias = b_refer[co];
                u16* dst = &kf16[((size_t)b * NC + co) * NP + p0 + col];
                #pragma unroll
                for (int ni = 0; ni < 4; ++ni)
                    dst[ni << 4] = f2bf(acc[mi][ni][rr] + bias);
            }
        }
    } else {
        // ---- heads via MFMA -> LDS transpose -> softmaxes + bilinear meta ----
        const int pt = (int)blockIdx.x - 512;
        const int b  = pt & 7;                 // XCD = batch (matches sample_pass)
        const int p0 = (pt >> 3) << 7;
        u16   (*A)[264] = (u16(*)[264])smem;               // 25344 B
        float (*hdT)[41] = (float(*)[41])(smem + 25344);   // 20992 B
        const int wn = wid;                    // 4 waves, 32 px each

        for (int i = t; i < 1152; i += 256) {  // 36 rows x 32 octets
            int o = i >> 5, c = (i & 31) << 3;
            const float* src = (o < 9) ? &w_attn[o * NC + c]
                           : (o < 18 ? &w_mask[(o - 9) * NC + c]
                                     : &w_off[(o - 18) * NC + c]);
            float4 v0 = *(const float4*)src;
            float4 v1 = *(const float4*)(src + 4);
            bf16x8 a;
            a[0] = (short)f2bf(v0.x); a[1] = (short)f2bf(v0.y);
            a[2] = (short)f2bf(v0.z); a[3] = (short)f2bf(v0.w);
            a[4] = (short)f2bf(v1.x); a[5] = (short)f2bf(v1.y);
            a[6] = (short)f2bf(v1.z); a[7] = (short)f2bf(v1.w);
            *(bf16x8*)&A[o][c] = a;
        }
        for (int i = t; i < 384; i += 256) {
            bf16x8 z = {0,0,0,0,0,0,0,0};
            *(bf16x8*)&A[36 + (i >> 5)][(i & 31) << 3] = z;
        }
        __syncthreads();

        f32x4 acc[3][2];
        #pragma unroll
        for (int i = 0; i < 3; ++i)
            #pragma unroll
            for (int j = 0; j < 2; ++j) acc[i][j] = (f32x4){0.f, 0.f, 0.f, 0.f};

        for (int ks = 0; ks < 8; ++ks) {
            const int k0 = (ks << 5) + kq;
            bf16x8 af[3], bfv[2];
            #pragma unroll
            for (int mi = 0; mi < 3; ++mi)
                af[mi] = *(const bf16x8*)&A[(mi << 4) + fr][k0];
            #pragma unroll
            for (int ni = 0; ni < 2; ++ni) {
                const float* src = &query[((size_t)b * NC + k0) * NP + p0 + (wn << 5) + (ni << 4) + fr];
                bf16x8 bv;
                #pragma unroll
                for (int j = 0; j < 8; ++j) bv[j] = (short)f2bf(src[(size_t)j * NP]);
                bfv[ni] = bv;
            }
            #pragma unroll
            for (int mi = 0; mi < 3; ++mi)
                #pragma unroll
                for (int ni = 0; ni < 2; ++ni)
                    acc[mi][ni] = __builtin_amdgcn_mfma_f32_16x16x32_bf16(af[mi], bfv[ni], acc[mi][ni], 0, 0, 0);
        }
        const int col = lane & 15, rbase = (lane >> 4) << 2;
        #pragma unroll
        for (int mi = 0; mi < 3; ++mi) {
            #pragma unroll
            for (int rr = 0; rr < 4; ++rr) {
                int o = (mi << 4) + rbase + rr;
                if (o < 36) {
                    float bias = (o < 9) ? b_attn[o] : (o < 18) ? b_mask[o - 9] : b_off[o - 18];
                    #pragma unroll
                    for (int ni = 0; ni < 2; ++ni)
                        hdT[(wn << 5) + (ni << 4) + col][o] = acc[mi][ni][rr] + bias;
                }
            }
        }
        __syncthreads();

        if (t < 128) {
            const int pxg = p0 + t;
            const int row = pxg >> 6, xcol = pxg & 63;
            float v[36];
            #pragma unroll
            for (int o = 0; o < 36; ++o) v[o] = hdT[t][o];

            int ti = temp_p[0];
            float tempf = (ti >= 1 && ti < (1 << 23)) ? (float)ti : __int_as_float(ti);
            float am[9], hs[9];
            float mx = -1e30f;
            #pragma unroll
            for (int k = 0; k < 9; ++k) {
                am[k] = v[k];
                float g = gumbel[((size_t)b * NK + k) * NP + pxg];
                hs[k] = (v[9 + k] + g) / tempf;
                mx = fmaxf(mx, hs[k]);
            }
            float ssum = 0.f;
            #pragma unroll
            for (int k = 0; k < 9; ++k) { hs[k] = __expf(hs[k] - mx); ssum += hs[k]; }
            float inv = 1.f / ssum;
            float lg[9]; float mx2 = -1e30f;
            #pragma unroll
            for (int k = 0; k < 9; ++k) { lg[k] = am[k] * (hs[k] * inv); mx2 = fmaxf(mx2, lg[k]); }
            float s2 = 0.f;
            #pragma unroll
            for (int k = 0; k < 9; ++k) { lg[k] = __expf(lg[k] - mx2); s2 += lg[k]; }
            float inv2 = 1.f / s2;
            #pragma unroll
            for (int k = 0; k < 9; ++k) {
                float a = lg[k] * inv2;
                float pyv = (float)row  + v[18 + k];       // dy = off chan k (bias folded)
                float pxv = (float)xcol + v[19 + k];       // dx = off chan k+1 (!)
                float y0f = floorf(pyv), x0f = floorf(pxv);
                float wy = pyv - y0f, wx = pxv - x0f;
                int y0 = (int)y0f, x0 = (int)x0f;
                int y1 = y0 + 1, x1 = x0 + 1;
                float vy0 = (y0 >= 0 && y0 < NH) ? 1.f : 0.f;
                float vy1 = (y1 >= 0 && y1 < NH) ? 1.f : 0.f;
                float vx0 = (x0 >= 0 && x0 < NW) ? 1.f : 0.f;
                float vx1 = (x1 >= 0 && x1 < NW) ? 1.f : 0.f;
                int y0c = min(max(y0, 0), NH - 1), y1c = min(max(y1, 0), NH - 1);
                int x0c = min(max(x0, 0), NW - 1), x1c = min(max(x1, 0), NW - 1);
                unsigned o00 = (unsigned)(y0c * NW + x0c), o01 = (unsigned)(y0c * NW + x1c);
                unsigned o10 = (unsigned)(y1c * NW + x0c), o11 = (unsigned)(y1c * NW + x1c);
                size_t idx = ((size_t)b * NK + k) * NP + pxg;
                wgt[idx]  = make_float4(a * (1.f - wy) * (1.f - wx) * vy0 * vx0,
                                        a * (1.f - wy) * wx * vy0 * vx1,
                                        a * wy * (1.f - wx) * vy1 * vx0,
                                        a * wy * wx * vy1 * vx1);
                offs[idx] = make_uint2(o00 | (o01 << 16), o10 | (o11 << 16));
            }
        }
    }
}

// ------- pass 2: banded scatter-GEMM: out[c][px] = kf16[c][band] @ S[band][px] -----------
__global__ __launch_bounds__(512, 4) void sample_pass(const u16* __restrict__ kf16,
                                                      const float4* __restrict__ wgt,
                                                      const uint2* __restrict__ offs,
                                                      float* __restrict__ out)
{
    __shared__ float Sf[64][BAND];                 // exactly 80 KB -> 2 blocks/CU

    const int bid = blockIdx.x;
    const int b = bid & 7, row = bid >> 3;         // b = XCD -> L2-resident kf16/meta
    const int t = threadIdx.x;
    const int lane = t & 63, wid = t >> 6;
    const int fr = lane & 15, kq = (lane >> 4) << 3;
    const int c0 = wid << 5;
    const int ylo = min(max(row - 2, 0), NH - 5);
    const int base = ylo << 6;
    const u16* kfb = kf16 + (size_t)b * NC * NP + base;

    // --- issue A prefetch at the very top: latency hides under zero+scatter+pack ---
    bf16x8 apre[4][2];
    #pragma unroll
    for (int s = 0; s < 4; ++s)
        #pragma unroll
        for (int mi = 0; mi < 2; ++mi)
            apre[s][mi] = *(const bf16x8*)&kfb[(size_t)(c0 + (mi << 4) + fr) * NP + (s << 5) + kq];

    // --- prefetch meta (consumed in scatter) ---
    const int px = t & 63, kg = t >> 6;
    size_t idx0 = ((size_t)b * NK + kg) * NP + (row << 6) + px;
    float4 wv0 = wgt[idx0];
    uint2  ov0 = offs[idx0];
    float4 wv1 = make_float4(0.f, 0.f, 0.f, 0.f);
    uint2  ov1 = make_uint2(0u, 0u);
    if (kg == 0) {
        size_t idx1 = ((size_t)b * NK + 8) * NP + (row << 6) + px;
        wv1 = wgt[idx1]; ov1 = offs[idx1];
    }

    // --- zero S ---
    #pragma unroll
    for (int i = 0; i < 10; ++i)
        ((float4*)Sf)[t + (i << 9)] = (float4){0.f, 0.f, 0.f, 0.f};
    __syncthreads();

    // --- scatter 36 weighted corners per px (f32 atomics; escapes -> flag) ---
    bool esc = false;
    #pragma unroll
    for (int s = 0; s < 2; ++s) {
        if (s == 1 && kg != 0) break;
        float4 wv = s ? wv1 : wv0;
        uint2  ov = s ? ov1 : ov0;
        int   o4[4] = { (int)(ov.x & 0xffffu), (int)(ov.x >> 16),
                        (int)(ov.y & 0xffffu), (int)(ov.y >> 16) };
        float w4[4] = { wv.x, wv.y, wv.z, wv.w };
        #pragma unroll
        for (int c = 0; c < 4; ++c) {
            int u = o4[c] - base;
            if ((unsigned)u < (unsigned)BAND) atomicAdd(&Sf[px][u], w4[c]);
            else esc = true;
        }
    }
    __syncthreads();

    // --- in-place pack S -> bf16: read ALL, one barrier, write ALL (no clobber) ---
    u16* Sb = (u16*)&Sf[0][0];                     // stride SB_STRIDE u16 (656B rows)
    bf16x8 pk[5]; int po[5];
    #pragma unroll
    for (int r = 0; r < 5; ++r) {
        int i = t + (r << 9);
        int p = i / 40, j = (i % 40) << 3;
        float4 a = *(const float4*)&Sf[p][j];
        float4 c = *(const float4*)&Sf[p][j + 4];
        bf16x8 q;
        q[0] = (short)f2bf(a.x); q[1] = (short)f2bf(a.y);
        q[2] = (short)f2bf(a.z); q[3] = (short)f2bf(a.w);
        q[4] = (short)f2bf(c.x); q[5] = (short)f2bf(c.y);
        q[6] = (short)f2bf(c.z); q[7] = (short)f2bf(c.w);
        pk[r] = q; po[r] = p * SB_STRIDE + j;
    }
    __syncthreads();
    #pragma unroll
    for (int r = 0; r < 5; ++r)
        *(bf16x8*)&Sb[po[r]] = pk[r];
    __syncthreads();

    // --- MFMA: wave w -> c rows [w*32, w*32+32), 64 px, K = 320; A pipelined 4 deep ---
    f32x4 acc[2][4];
    #pragma unroll
    for (int i = 0; i < 2; ++i)
        #pragma unroll
        for (int j = 0; j < 4; ++j) acc[i][j] = (f32x4){0.f, 0.f, 0.f, 0.f};

    #pragma unroll
    for (int step = 0; step < 10; ++step) {
        bf16x8 a0 = apre[step & 3][0], a1 = apre[step & 3][1];
        if (step + 4 < 10) {
            #pragma unroll
            for (int mi = 0; mi < 2; ++mi)
                apre[step & 3][mi] =
                    *(const bf16x8*)&kfb[(size_t)(c0 + (mi << 4) + fr) * NP + ((step + 4) << 5) + kq];
        }
        bf16x8 bfv[4];
        #pragma unroll
        for (int ni = 0; ni < 4; ++ni)
            bfv[ni] = *(const bf16x8*)&Sb[((ni << 4) + fr) * SB_STRIDE + (step << 5) + kq];
        #pragma unroll
        for (int ni = 0; ni < 4; ++ni) {
            acc[0][ni] = __builtin_amdgcn_mfma_f32_16x16x32_bf16(a0, bfv[ni], acc[0][ni], 0, 0, 0);
            acc[1][ni] = __builtin_amdgcn_mfma_f32_16x16x32_bf16(a1, bfv[ni], acc[1][ni], 0, 0, 0);
        }
    }

    // --- store (block-exclusive out region) ---
    const int col = lane & 15, rbase = (lane >> 4) << 2;
    float* ob = out + (size_t)b * NC * NP + (row << 6);
    #pragma unroll
    for (int mi = 0; mi < 2; ++mi) {
        #pragma unroll
        for (int rr = 0; rr < 4; ++rr) {
            int c = c0 + (mi << 4) + rbase + rr;
            #pragma unroll
            for (int ni = 0; ni < 4; ++ni)
                ob[(size_t)c * NP + (ni << 4) + col] = acc[mi][ni][rr];
        }
    }

    // --- rare out-of-band corners (exact fallback; ~never executes) ---
    __syncthreads();
    if (esc) {
        for (int s = 0; s < (kg == 0 ? 2 : 1); ++s) {
            int k = s ? 8 : kg;
            size_t idx = ((size_t)b * NK + k) * NP + (row << 6) + px;
            float4 wv = wgt[idx];
            uint2  ov = offs[idx];
            int   o4[4] = { (int)(ov.x & 0xffffu), (int)(ov.x >> 16),
                            (int)(ov.y & 0xffffu), (int)(ov.y >> 16) };
            float w4[4] = { wv.x, wv.y, wv.z, wv.w };
            for (int c = 0; c < 4; ++c) {
                int u = o4[c] - base;
                if ((unsigned)u >= (unsigned)BAND) {
                    for (int cc = 0; cc < NC; ++cc)
                        atomicAdd(&ob[(size_t)cc * NP + px],
                                  w4[c] * bf2f(kf16[((size_t)b * NC + cc) * NP + o4[c]]));
                }
            }
        }
    }
}

extern "C" void kernel_launch(void* const* d_in, const int* in_sizes, int n_in,
                              void* d_out, int out_size, void* d_ws, size_t ws_size,
                              hipStream_t stream)
{
    const float* query   = (const float*)d_in[0];
    const float* key     = (const float*)d_in[1];
    const float* gumbel  = (const float*)d_in[2];
    const float* w_refer = (const float*)d_in[3];
    const float* b_refer = (const float*)d_in[4];
    const float* w_attn  = (const float*)d_in[5];
    const float* b_attn  = (const float*)d_in[6];
    const float* w_mask  = (const float*)d_in[7];
    const float* b_mask  = (const float*)d_in[8];
    const float* w_off   = (const float*)d_in[9];
    const float* b_off   = (const float*)d_in[10];
    const int*   temp    = (const int*)d_in[11];
    float* out = (float*)d_out;

    u16*    kf16 = (u16*)d_ws;                                          // 16.78 MB
    float4* wgt  = (float4*)((char*)d_ws + (size_t)NB * NP * NC * 2);   // 4.72 MB
    uint2*  offs = (uint2*)((char*)wgt + (size_t)NB * NK * NP * 16);    // 2.36 MB

    prep<<<768, 256, 0, stream>>>(key, query, gumbel, w_refer, b_refer,
                                  w_attn, b_attn, w_mask, b_mask, w_off, b_off,
                                  temp, kf16, wgt, offs);
    sample_pass<<<512, 512, 0, stream>>>(kf16, wgt, offs, out);
}

// Round 8
// 61.140 us; speedup vs baseline: 1.0778x; 1.0778x over previous
//
#include <hip/hip_runtime.h>

typedef unsigned short u16;
typedef __attribute__((ext_vector_type(8))) short bf16x8;
typedef __attribute__((ext_vector_type(4))) float f32x4;

__device__ __forceinline__ u16 f2bf(float f) {
    unsigned u = __float_as_uint(f);
    unsigned r = (u + 0x7fffu + ((u >> 16) & 1u)) >> 16;
    return (u16)r;
}
__device__ __forceinline__ float bf2f(u16 h) {
    union { unsigned u; float f; } x; x.u = ((unsigned)h) << 16; return x.f;
}

#define NB 8
#define NC 256
#define NK 9
#define NH 64
#define NW 64
#define NP 4096
#define BAND 320            // 5 rows x 64 px band; escapes handled exactly
#define SB_STRIDE 328       // u16 stride for in-place bf16 B tile (656B rows)
#define HW_STRIDE 264       // u16 stride of prebuilt head-weight table (528B rows)

// ---- pass 0: one-time weight conversion: wb16[co][k], hw16[48][264] (padded+zeroed) ----
__global__ __launch_bounds__(256) void wconv(const float* __restrict__ w_refer,
                                             const float* __restrict__ w_attn,
                                             const float* __restrict__ w_mask,
                                             const float* __restrict__ w_off,
                                             u16* __restrict__ wb16, u16* __restrict__ hw16)
{
    const int bid = blockIdx.x, t = threadIdx.x;
    if (bid < 64) {
        int idx = bid * 256 + t;               // 16384 quads
        int co = idx >> 6, k4 = (idx & 63) << 2;
        float4 v = *(const float4*)&w_refer[co * NC + k4];
        u16* d = &wb16[co * NC + k4];
        d[0] = f2bf(v.x); d[1] = f2bf(v.y); d[2] = f2bf(v.z); d[3] = f2bf(v.w);
    } else {
        for (int i = (bid - 64) * 1584 + t; i < (bid - 63) * 1584; i += 256) {
            int r = i / HW_STRIDE, c = i % HW_STRIDE;
            float v = 0.f;
            if (r < 36 && c < 256)
                v = (r < 9) ? w_attn[r * NC + c]
                  : (r < 18 ? w_mask[(r - 9) * NC + c] : w_off[(r - 18) * NC + c]);
            hw16[i] = f2bf(v);
        }
    }
}

// -------- pass 1: kf16[b][c][px] = bf16(wb16 @ key + b_refer), LDS-free, pipelined --------
__global__ __launch_bounds__(256) void kf_gemm(const float* __restrict__ key,
                                               const u16* __restrict__ wb16,
                                               const float* __restrict__ b_refer,
                                               u16* __restrict__ kf16)
{
    const int bid = blockIdx.x;            // 512 = 64 px-tiles x 8 b
    const int b   = bid & 7;               // XCD = batch (matches sample_pass)
    const int p0  = (bid >> 3) << 6;
    const int lane = threadIdx.x & 63, wid = threadIdx.x >> 6;
    const int fr = lane & 15, kq = (lane >> 4) << 3;
    const int co0w = wid << 6;             // wave covers co [co0w, co0w+64)

    f32x4 acc[4][4];
    #pragma unroll
    for (int i = 0; i < 4; ++i)
        #pragma unroll
        for (int j = 0; j < 4; ++j) acc[i][j] = (f32x4){0.f, 0.f, 0.f, 0.f};

    const float* kb = &key[(size_t)b * NC * NP + p0];

#define LOAD_A(ks, dst)                                                            \
    {   _Pragma("unroll")                                                          \
        for (int mi = 0; mi < 4; ++mi)                                             \
            dst[mi] = *(const bf16x8*)&wb16[(size_t)(co0w + (mi << 4) + fr) * NC + ((ks) << 5) + kq]; }
#define LOAD_B(ks, dst)                                                            \
    {   _Pragma("unroll")                                                          \
        for (int ni = 0; ni < 4; ++ni) {                                           \
            const float* src = &kb[(size_t)(((ks) << 5) + kq) * NP + (ni << 4) + fr]; \
            bf16x8 bv;                                                             \
            _Pragma("unroll")                                                      \
            for (int j = 0; j < 8; ++j) bv[j] = (short)f2bf(src[(size_t)j * NP]);  \
            dst[ni] = bv; } }

    bf16x8 aP[4], bP[4], aQ[4], bQ[4];
    LOAD_A(0, aP); LOAD_B(0, bP);
    #pragma unroll
    for (int ks = 0; ks < 8; ++ks) {
        if (ks & 1) {
            if (ks < 7) { LOAD_A(ks + 1, aP); LOAD_B(ks + 1, bP); }
            #pragma unroll
            for (int mi = 0; mi < 4; ++mi)
                #pragma unroll
                for (int ni = 0; ni < 4; ++ni)
                    acc[mi][ni] = __builtin_amdgcn_mfma_f32_16x16x32_bf16(aQ[mi], bQ[ni], acc[mi][ni], 0, 0, 0);
        } else {
            if (ks < 7) { LOAD_A(ks + 1, aQ); LOAD_B(ks + 1, bQ); }
            #pragma unroll
            for (int mi = 0; mi < 4; ++mi)
                #pragma unroll
                for (int ni = 0; ni < 4; ++ni)
                    acc[mi][ni] = __builtin_amdgcn_mfma_f32_16x16x32_bf16(aP[mi], bP[ni], acc[mi][ni], 0, 0, 0);
        }
    }
#undef LOAD_A
#undef LOAD_B

    const int col = lane & 15, rbase = (lane >> 4) << 2;
    #pragma unroll
    for (int mi = 0; mi < 4; ++mi) {
        #pragma unroll
        for (int rr = 0; rr < 4; ++rr) {
            int co = co0w + (mi << 4) + rbase + rr;
            float bias = b_refer[co];
            u16* dst = &kf16[((size_t)b * NC + co) * NP + p0 + col];
            #pragma unroll
            for (int ni = 0; ni < 4; ++ni)
                dst[ni << 4] = f2bf(acc[mi][ni][rr] + bias);
        }
    }
}

// ---- pass 2: heads via MFMA -> LDS transpose -> softmaxes + bilinear meta (fused) ----
__global__ __launch_bounds__(256) void head_meta(const float* __restrict__ query,
                                                 const float* __restrict__ gumbel,
                                                 const u16* __restrict__ hw16,
                                                 const float* __restrict__ b_attn,
                                                 const float* __restrict__ b_mask,
                                                 const float* __restrict__ b_off,
                                                 const int* __restrict__ temp_p,
                                                 float4* __restrict__ wgt, uint2* __restrict__ offs)
{
    __shared__ u16 A[48][HW_STRIDE];       // prebuilt bf16 head weights, 25.3 KB
    __shared__ float hdT[128][41];         // transposed head outputs [px][o], 21 KB
    const int pt = blockIdx.x;             // 256 tiles of 128 px
    const int b  = pt & 7;                 // XCD = batch (matches sample_pass)
    const int p0 = (pt >> 3) << 7;
    const int t = threadIdx.x;
    const int lane = t & 63, wn = t >> 6;  // 4 waves, 32 px each
    const int fr = lane & 15, kq = (lane >> 4) << 3;

    // straight 16B copy of the prebuilt table
    #pragma unroll
    for (int i = t; i < 1584; i += 256)
        ((uint4*)A)[i] = ((const uint4*)hw16)[i];
    __syncthreads();

    f32x4 acc[3][2];
    #pragma unroll
    for (int i = 0; i < 3; ++i)
        #pragma unroll
        for (int j = 0; j < 2; ++j) acc[i][j] = (f32x4){0.f, 0.f, 0.f, 0.f};

    for (int ks = 0; ks < 8; ++ks) {
        const int k0 = (ks << 5) + kq;
        bf16x8 af[3], bfv[2];
        #pragma unroll
        for (int mi = 0; mi < 3; ++mi)
            af[mi] = *(const bf16x8*)&A[(mi << 4) + fr][k0];
        #pragma unroll
        for (int ni = 0; ni < 2; ++ni) {
            const float* src = &query[((size_t)b * NC + k0) * NP + p0 + (wn << 5) + (ni << 4) + fr];
            bf16x8 bv;
            #pragma unroll
            for (int j = 0; j < 8; ++j) bv[j] = (short)f2bf(src[(size_t)j * NP]);
            bfv[ni] = bv;
        }
        #pragma unroll
        for (int mi = 0; mi < 3; ++mi)
            #pragma unroll
            for (int ni = 0; ni < 2; ++ni)
                acc[mi][ni] = __builtin_amdgcn_mfma_f32_16x16x32_bf16(af[mi], bfv[ni], acc[mi][ni], 0, 0, 0);
    }
    const int col = lane & 15, rbase = (lane >> 4) << 2;
    #pragma unroll
    for (int mi = 0; mi < 3; ++mi) {
        #pragma unroll
        for (int rr = 0; rr < 4; ++rr) {
            int o = (mi << 4) + rbase + rr;
            if (o < 36) {
                float bias = (o < 9) ? b_attn[o] : (o < 18) ? b_mask[o - 9] : b_off[o - 18];
                #pragma unroll
                for (int ni = 0; ni < 2; ++ni)
                    hdT[(wn << 5) + (ni << 4) + col][o] = acc[mi][ni][rr] + bias;
            }
        }
    }
    __syncthreads();

    if (t < 128) {
        const int pxg = p0 + t;
        const int row = pxg >> 6, xcol = pxg & 63;
        float v[36];
        #pragma unroll
        for (int o = 0; o < 36; ++o) v[o] = hdT[t][o];

        int ti = temp_p[0];
        float tempf = (ti >= 1 && ti < (1 << 23)) ? (float)ti : __int_as_float(ti);
        float am[9], hs[9];
        float mx = -1e30f;
        #pragma unroll
        for (int k = 0; k < 9; ++k) {
            am[k] = v[k];
            float g = gumbel[((size_t)b * NK + k) * NP + pxg];
            hs[k] = (v[9 + k] + g) / tempf;
            mx = fmaxf(mx, hs[k]);
        }
        float ssum = 0.f;
        #pragma unroll
        for (int k = 0; k < 9; ++k) { hs[k] = __expf(hs[k] - mx); ssum += hs[k]; }
        float inv = 1.f / ssum;
        float lg[9]; float mx2 = -1e30f;
        #pragma unroll
        for (int k = 0; k < 9; ++k) { lg[k] = am[k] * (hs[k] * inv); mx2 = fmaxf(mx2, lg[k]); }
        float s2 = 0.f;
        #pragma unroll
        for (int k = 0; k < 9; ++k) { lg[k] = __expf(lg[k] - mx2); s2 += lg[k]; }
        float inv2 = 1.f / s2;
        #pragma unroll
        for (int k = 0; k < 9; ++k) {
            float a = lg[k] * inv2;
            float pyv = (float)row  + v[18 + k];       // dy = off chan k (bias folded)
            float pxv = (float)xcol + v[19 + k];       // dx = off chan k+1 (!)
            float y0f = floorf(pyv), x0f = floorf(pxv);
            float wy = pyv - y0f, wx = pxv - x0f;
            int y0 = (int)y0f, x0 = (int)x0f;
            int y1 = y0 + 1, x1 = x0 + 1;
            float vy0 = (y0 >= 0 && y0 < NH) ? 1.f : 0.f;
            float vy1 = (y1 >= 0 && y1 < NH) ? 1.f : 0.f;
            float vx0 = (x0 >= 0 && x0 < NW) ? 1.f : 0.f;
            float vx1 = (x1 >= 0 && x1 < NW) ? 1.f : 0.f;
            int y0c = min(max(y0, 0), NH - 1), y1c = min(max(y1, 0), NH - 1);
            int x0c = min(max(x0, 0), NW - 1), x1c = min(max(x1, 0), NW - 1);
            unsigned o00 = (unsigned)(y0c * NW + x0c), o01 = (unsigned)(y0c * NW + x1c);
            unsigned o10 = (unsigned)(y1c * NW + x0c), o11 = (unsigned)(y1c * NW + x1c);
            size_t idx = ((size_t)b * NK + k) * NP + pxg;
            wgt[idx]  = make_float4(a * (1.f - wy) * (1.f - wx) * vy0 * vx0,
                                    a * (1.f - wy) * wx * vy0 * vx1,
                                    a * wy * (1.f - wx) * vy1 * vx0,
                                    a * wy * wx * vy1 * vx1);
            offs[idx] = make_uint2(o00 | (o01 << 16), o10 | (o11 << 16));
        }
    }
}

// ------- pass 3: banded scatter-GEMM: out[c][px] = kf16[c][band] @ S[band][px] -----------
__global__ __launch_bounds__(512, 4) void sample_pass(const u16* __restrict__ kf16,
                                                      const float4* __restrict__ wgt,
                                                      const uint2* __restrict__ offs,
                                                      float* __restrict__ out)
{
    __shared__ float Sf[64][BAND];                 // exactly 80 KB -> 2 blocks/CU

    const int bid = blockIdx.x;
    const int b = bid & 7, row = bid >> 3;         // b = XCD -> L2-resident kf16/meta
    const int t = threadIdx.x;
    const int lane = t & 63, wid = t >> 6;
    const int fr = lane & 15, kq = (lane >> 4) << 3;
    const int c0 = wid << 5;
    const int ylo = min(max(row - 2, 0), NH - 5);
    const int base = ylo << 6;
    const u16* kfb = kf16 + (size_t)b * NC * NP + base;

    // --- issue A prefetch at the very top: latency hides under zero+scatter+pack ---
    bf16x8 apre[4][2];
    #pragma unroll
    for (int s = 0; s < 4; ++s)
        #pragma unroll
        for (int mi = 0; mi < 2; ++mi)
            apre[s][mi] = *(const bf16x8*)&kfb[(size_t)(c0 + (mi << 4) + fr) * NP + (s << 5) + kq];

    // --- prefetch meta (consumed in scatter) ---
    const int px = t & 63, kg = t >> 6;
    size_t idx0 = ((size_t)b * NK + kg) * NP + (row << 6) + px;
    float4 wv0 = wgt[idx0];
    uint2  ov0 = offs[idx0];
    float4 wv1 = make_float4(0.f, 0.f, 0.f, 0.f);
    uint2  ov1 = make_uint2(0u, 0u);
    if (kg == 0) {
        size_t idx1 = ((size_t)b * NK + 8) * NP + (row << 6) + px;
        wv1 = wgt[idx1]; ov1 = offs[idx1];
    }

    // --- zero S ---
    #pragma unroll
    for (int i = 0; i < 10; ++i)
        ((float4*)Sf)[t + (i << 9)] = (float4){0.f, 0.f, 0.f, 0.f};
    __syncthreads();

    // --- scatter 36 weighted corners per px (f32 atomics; escapes -> flag) ---
    bool esc = false;
    #pragma unroll
    for (int s = 0; s < 2; ++s) {
        if (s == 1 && kg != 0) break;
        float4 wv = s ? wv1 : wv0;
        uint2  ov = s ? ov1 : ov0;
        int   o4[4] = { (int)(ov.x & 0xffffu), (int)(ov.x >> 16),
                        (int)(ov.y & 0xffffu), (int)(ov.y >> 16) };
        float w4[4] = { wv.x, wv.y, wv.z, wv.w };
        #pragma unroll
        for (int c = 0; c < 4; ++c) {
            int u = o4[c] - base;
            if ((unsigned)u < (unsigned)BAND) atomicAdd(&Sf[px][u], w4[c]);
            else esc = true;
        }
    }
    __syncthreads();

    // --- in-place pack S -> bf16: read ALL, one barrier, write ALL (no clobber) ---
    u16* Sb = (u16*)&Sf[0][0];                     // stride SB_STRIDE u16 (656B rows)
    bf16x8 pk[5]; int po[5];
    #pragma unroll
    for (int r = 0; r < 5; ++r) {
        int i = t + (r << 9);
        int p = i / 40, j = (i % 40) << 3;
        float4 a = *(const float4*)&Sf[p][j];
        float4 c = *(const float4*)&Sf[p][j + 4];
        bf16x8 q;
        q[0] = (short)f2bf(a.x); q[1] = (short)f2bf(a.y);
        q[2] = (short)f2bf(a.z); q[3] = (short)f2bf(a.w);
        q[4] = (short)f2bf(c.x); q[5] = (short)f2bf(c.y);
        q[6] = (short)f2bf(c.z); q[7] = (short)f2bf(c.w);
        pk[r] = q; po[r] = p * SB_STRIDE + j;
    }
    __syncthreads();
    #pragma unroll
    for (int r = 0; r < 5; ++r)
        *(bf16x8*)&Sb[po[r]] = pk[r];
    __syncthreads();

    // --- MFMA: wave w -> c rows [w*32, w*32+32), 64 px, K = 320; A pipelined 4 deep ---
    f32x4 acc[2][4];
    #pragma unroll
    for (int i = 0; i < 2; ++i)
        #pragma unroll
        for (int j = 0; j < 4; ++j) acc[i][j] = (f32x4){0.f, 0.f, 0.f, 0.f};

    #pragma unroll
    for (int step = 0; step < 10; ++step) {
        bf16x8 a0 = apre[step & 3][0], a1 = apre[step & 3][1];
        if (step + 4 < 10) {
            #pragma unroll
            for (int mi = 0; mi < 2; ++mi)
                apre[step & 3][mi] =
                    *(const bf16x8*)&kfb[(size_t)(c0 + (mi << 4) + fr) * NP + ((step + 4) << 5) + kq];
        }
        bf16x8 bfv[4];
        #pragma unroll
        for (int ni = 0; ni < 4; ++ni)
            bfv[ni] = *(const bf16x8*)&Sb[((ni << 4) + fr) * SB_STRIDE + (step << 5) + kq];
        #pragma unroll
        for (int ni = 0; ni < 4; ++ni) {
            acc[0][ni] = __builtin_amdgcn_mfma_f32_16x16x32_bf16(a0, bfv[ni], acc[0][ni], 0, 0, 0);
            acc[1][ni] = __builtin_amdgcn_mfma_f32_16x16x32_bf16(a1, bfv[ni], acc[1][ni], 0, 0, 0);
        }
    }

    // --- store (block-exclusive out region) ---
    const int col = lane & 15, rbase = (lane >> 4) << 2;
    float* ob = out + (size_t)b * NC * NP + (row << 6);
    #pragma unroll
    for (int mi = 0; mi < 2; ++mi) {
        #pragma unroll
        for (int rr = 0; rr < 4; ++rr) {
            int c = c0 + (mi << 4) + rbase + rr;
            #pragma unroll
            for (int ni = 0; ni < 4; ++ni)
                ob[(size_t)c * NP + (ni << 4) + col] = acc[mi][ni][rr];
        }
    }

    // --- rare out-of-band corners (exact fallback; ~never executes) ---
    __syncthreads();
    if (esc) {
        for (int s = 0; s < (kg == 0 ? 2 : 1); ++s) {
            int k = s ? 8 : kg;
            size_t idx = ((size_t)b * NK + k) * NP + (row << 6) + px;
            float4 wv = wgt[idx];
            uint2  ov = offs[idx];
            int   o4[4] = { (int)(ov.x & 0xffffu), (int)(ov.x >> 16),
                            (int)(ov.y & 0xffffu), (int)(ov.y >> 16) };
            float w4[4] = { wv.x, wv.y, wv.z, wv.w };
            for (int c = 0; c < 4; ++c) {
                int u = o4[c] - base;
                if ((unsigned)u >= (unsigned)BAND) {
                    for (int cc = 0; cc < NC; ++cc)
                        atomicAdd(&ob[(size_t)cc * NP + px],
                                  w4[c] * bf2f(kf16[((size_t)b * NC + cc) * NP + o4[c]]));
                }
            }
        }
    }
}

extern "C" void kernel_launch(void* const* d_in, const int* in_sizes, int n_in,
                              void* d_out, int out_size, void* d_ws, size_t ws_size,
                              hipStream_t stream)
{
    const float* query   = (const float*)d_in[0];
    const float* key     = (const float*)d_in[1];
    const float* gumbel  = (const float*)d_in[2];
    const float* w_refer = (const float*)d_in[3];
    const float* b_refer = (const float*)d_in[4];
    const float* w_attn  = (const float*)d_in[5];
    const float* b_attn  = (const float*)d_in[6];
    const float* w_mask  = (const float*)d_in[7];
    const float* b_mask  = (const float*)d_in[8];
    const float* w_off   = (const float*)d_in[9];
    const float* b_off   = (const float*)d_in[10];
    const int*   temp    = (const int*)d_in[11];
    float* out = (float*)d_out;

    char* ws = (char*)d_ws;
    u16*    kf16 = (u16*)ws;                                   // 16.78 MB
    float4* wgt  = (float4*)(ws + (size_t)NB * NP * NC * 2);   // 4.72 MB
    uint2*  offs = (uint2*)((char*)wgt + (size_t)NB * NK * NP * 16);   // 2.36 MB
    u16*    wb16 = (u16*)((char*)offs + (size_t)NB * NK * NP * 8);     // 128 KB
    u16*    hw16 = (u16*)((char*)wb16 + (size_t)NC * NC * 2);          // 25.3 KB

    wconv<<<72, 256, 0, stream>>>(w_refer, w_attn, w_mask, w_off, wb16, hw16);
    kf_gemm<<<512, 256, 0, stream>>>(key, wb16, b_refer, kf16);
    head_meta<<<256, 256, 0, stream>>>(query, gumbel, hw16, b_attn, b_mask, b_off,
                                       temp, wgt, offs);
    sample_pass<<<512, 512, 0, stream>>>(kf16, wgt, offs, out);
}